// Round 3
// baseline (205.851 us; speedup 1.0000x reference)
//
#include <hip/hip_runtime.h>

#define NB   32
#define TMAX 512
#define DDIM 384
#define TOUT (TMAX * 7)      // 3584
#define D4   (DDIM / 4)      // 96 float4 per frame
#define FPB  64              // frames per block
#define NTH  256             // threads per block (4 waves)
#define ITER (FPB * D4 / NTH) // 24 float4 per thread

typedef float v4f __attribute__((ext_vector_type(4)));

// Fused kernel: every block recomputes its batch's masked duration cumsum
// (512 elems, shuffle scan), binary-searches its FPB frames, and streams
// FPB*96 float4 = 96 KB of contiguous output via nontemporal stores.
// Grid: (TOUT/FPB, B) = (56, 32) = 1792 blocks.
__global__ __launch_bounds__(NTH) void lr_fused_kernel(
        const v4f* __restrict__ xs,
        const int* __restrict__ ds,
        const int* __restrict__ ilens,
        v4f*       __restrict__ out) {
    __shared__ int s_cum[TMAX];
    __shared__ int s_wsum[NTH / 64];
    __shared__ int s_idx[FPB];

    const int b    = blockIdx.y;
    const int f0   = blockIdx.x * FPB;
    const int t    = threadIdx.x;
    const int lane = t & 63;
    const int wid  = t >> 6;

    const int len = ilens[b];

    // ---- masked cumsum of ds: 512 elems, 2 per thread -------------------
    const int2 dv = reinterpret_cast<const int2*>(ds + b * TMAX)[t];
    const int e0 = 2 * t, e1 = 2 * t + 1;
    const int a = (e0 < len) ? dv.x : 0;
    const int c = (e1 < len) ? dv.y : 0;

    int x = a + c;
#pragma unroll
    for (int off = 1; off < 64; off <<= 1) {
        int v = __shfl_up(x, off);
        if (lane >= off) x += v;
    }
    if (lane == 63) s_wsum[wid] = x;
    __syncthreads();
    int prev = 0;
#pragma unroll
    for (int w = 0; w < NTH / 64; ++w)
        if (w < wid) prev += s_wsum[w];
    const int inc = x + prev;       // inclusive cumsum through element e1
    s_cum[e1] = inc;
    s_cum[e0] = inc - c;
    __syncthreads();

    int total = s_cum[TMAX - 1];
    if (total == 0) {               // uniform branch per block
        // fallback d = mask  =>  cum[t] = min(t+1, len), closed form
        __syncthreads();
        s_cum[e0] = min(e0 + 1, len);
        s_cum[e1] = min(e1 + 1, len);
        total = len;
        __syncthreads();
    }

    // ---- searchsorted(cum, f, side='right') for this block's frames -----
    if (t < FPB) {
        const int f = f0 + t;
        int lo = 0, hi = TMAX;
        while (lo < hi) {
            int mid = (lo + hi) >> 1;
            if (s_cum[mid] > f) hi = mid; else lo = mid + 1;
        }
        s_idx[t] = (lo < TMAX) ? lo : (TMAX - 1);
    }
    __syncthreads();

    // ---- expand: FPB*96 = 6144 float4, 24 per thread, fully contiguous --
    const int base_out = (b * TOUT + f0) * D4;
    const int base_xs  = b * TMAX * D4;
#pragma unroll
    for (int i = 0; i < ITER; ++i) {
        const int l   = i * NTH + t;    // contiguous across threads
        const int fl  = l / D4;         // local frame 0..63
        const int col = l - fl * D4;    // 0..95
        v4f v = (v4f)(0.f);
        if (f0 + fl < total)
            v = xs[base_xs + s_idx[fl] * D4 + col];
        __builtin_nontemporal_store(v, &out[base_out + l]);
    }
}

extern "C" void kernel_launch(void* const* d_in, const int* in_sizes, int n_in,
                              void* d_out, int out_size, void* d_ws, size_t ws_size,
                              hipStream_t stream) {
    const float* xs    = (const float*)d_in[0];
    const int*   ds    = (const int*)d_in[1];
    const int*   ilens = (const int*)d_in[2];
    float*       out   = (float*)d_out;

    dim3 grid(TOUT / FPB, NB);   // 56 x 32
    lr_fused_kernel<<<grid, NTH, 0, stream>>>(
        (const v4f*)xs, ds, ilens, (v4f*)out);
}

// Round 4
// 205.638 us; speedup vs baseline: 1.0010x; 1.0010x over previous
//
#include <hip/hip_runtime.h>

#define NB   32
#define TMAX 512
#define DDIM 384
#define TOUT (TMAX * 7)      // 3584
#define D4   (DDIM / 4)      // 96 float4 per frame
#define FPB  64              // frames per block
#define NTH  256             // threads per block (4 waves)
#define ITER (FPB * D4 / NTH) // 24 float4 per thread
#define CPB  (TOUT / FPB)    // 56 chunks per batch
#define NBLK (NB * CPB)      // 1792 blocks total
#define NXCD 8
#define BPX  (NBLK / NXCD)   // 224 blocks per XCD = 4 batches

typedef float v4f __attribute__((ext_vector_type(4)));

// Fused kernel with XCD-aware block swizzle: blocks are assigned so each
// XCD (blockIdx % 8 under round-robin dispatch) owns 4 whole batches ->
// its private L2 fetches only those batches' xs (3.2 MB vs 25 MB).
// Each block: recompute batch cumsum (shuffle scan), binary-search FPB
// frames, stream FPB*96 float4 = 96 KB contiguous nontemporal stores.
__global__ __launch_bounds__(NTH) void lr_fused_kernel(
        const v4f* __restrict__ xs,
        const int* __restrict__ ds,
        const int* __restrict__ ilens,
        v4f*       __restrict__ out) {
    __shared__ int s_cum[TMAX];
    __shared__ int s_wsum[NTH / 64];
    __shared__ int s_idx[FPB];

    // ---- XCD swizzle: bijective since NBLK % 8 == 0 ---------------------
    const int bid  = blockIdx.x;
    const int xcd  = bid & (NXCD - 1);
    const int slot = bid >> 3;              // 0..223
    const int work = xcd * BPX + slot;      // batch-major work id
    const int b    = work / CPB;            // batch 0..31 (4 per XCD)
    const int f0   = (work - b * CPB) * FPB;

    const int t    = threadIdx.x;
    const int lane = t & 63;
    const int wid  = t >> 6;

    const int len = ilens[b];

    // ---- masked cumsum of ds: 512 elems, 2 per thread -------------------
    const int2 dv = reinterpret_cast<const int2*>(ds + b * TMAX)[t];
    const int e0 = 2 * t, e1 = 2 * t + 1;
    const int a = (e0 < len) ? dv.x : 0;
    const int c = (e1 < len) ? dv.y : 0;

    int x = a + c;
#pragma unroll
    for (int off = 1; off < 64; off <<= 1) {
        int v = __shfl_up(x, off);
        if (lane >= off) x += v;
    }
    if (lane == 63) s_wsum[wid] = x;
    __syncthreads();
    int prev = 0;
#pragma unroll
    for (int w = 0; w < NTH / 64; ++w)
        if (w < wid) prev += s_wsum[w];
    const int inc = x + prev;       // inclusive cumsum through element e1
    s_cum[e1] = inc;
    s_cum[e0] = inc - c;
    __syncthreads();

    int total = s_cum[TMAX - 1];
    if (total == 0) {               // uniform branch per block
        // fallback d = mask  =>  cum[t] = min(t+1, len), closed form
        __syncthreads();
        s_cum[e0] = min(e0 + 1, len);
        s_cum[e1] = min(e1 + 1, len);
        total = len;
        __syncthreads();
    }

    // ---- searchsorted(cum, f, side='right') for this block's frames -----
    if (t < FPB) {
        const int f = f0 + t;
        int lo = 0, hi = TMAX;
        while (lo < hi) {
            int mid = (lo + hi) >> 1;
            if (s_cum[mid] > f) hi = mid; else lo = mid + 1;
        }
        s_idx[t] = (lo < TMAX) ? lo : (TMAX - 1);
    }
    __syncthreads();

    // ---- expand: FPB*96 = 6144 float4, 24 per thread, fully contiguous --
    const int base_out = (b * TOUT + f0) * D4;
    const int base_xs  = b * TMAX * D4;
#pragma unroll
    for (int i = 0; i < ITER; ++i) {
        const int l   = i * NTH + t;    // contiguous across threads
        const int fl  = l / D4;         // local frame 0..63
        const int col = l - fl * D4;    // 0..95
        v4f v = (v4f)(0.f);
        if (f0 + fl < total)
            v = xs[base_xs + s_idx[fl] * D4 + col];
        __builtin_nontemporal_store(v, &out[base_out + l]);
    }
}

extern "C" void kernel_launch(void* const* d_in, const int* in_sizes, int n_in,
                              void* d_out, int out_size, void* d_ws, size_t ws_size,
                              hipStream_t stream) {
    const float* xs    = (const float*)d_in[0];
    const int*   ds    = (const int*)d_in[1];
    const int*   ilens = (const int*)d_in[2];
    float*       out   = (float*)d_out;

    lr_fused_kernel<<<NBLK, NTH, 0, stream>>>(
        (const v4f*)xs, ds, ilens, (v4f*)out);
}

// Round 5
// 201.810 us; speedup vs baseline: 1.0200x; 1.0190x over previous
//
#include <hip/hip_runtime.h>

#define NB   32
#define TMAX 512
#define DDIM 384
#define TOUT (TMAX * 7)      // 3584
#define D4   (DDIM / 4)      // 96 float4 per frame
#define FPB  64              // frames per block
#define NTH  256             // threads per block (4 waves)
#define ITER (FPB * D4 / NTH) // 24 float4 per thread
#define BATCH 12             // loads in flight per thread in gather path
#define CPB  (TOUT / FPB)    // 56 chunks per batch
#define NBLK (NB * CPB)      // 1792 blocks
#define NXCD 8
#define BPX  (NBLK / NXCD)   // 224 blocks per XCD = 4 whole batches

typedef float v4f __attribute__((ext_vector_type(4)));

// Fused kernel, restructured around the pad/gather split:
//  - pad-only blocks (f0 >= total, ~75% of volume on avg) take a pure
//    zero-store stream identical in shape to the 6.8 TB/s fill kernel;
//  - gather blocks issue UNCONDITIONAL clamped loads in batches of 12
//    (12 outstanding per wave instead of 1), then cndmask-select pad
//    lanes and store. No branch around any global_load.
__global__ __launch_bounds__(NTH) void lr_fused_kernel(
        const v4f* __restrict__ xs,
        const int* __restrict__ ds,
        const int* __restrict__ ilens,
        v4f*       __restrict__ out) {
    __shared__ int s_cum[TMAX];
    __shared__ int s_wsum[NTH / 64];
    __shared__ int s_idx[FPB];

    // ---- XCD swizzle (bijective, NBLK % 8 == 0): 4 whole batches/XCD ----
    const int bid  = blockIdx.x;
    const int xcd  = bid & (NXCD - 1);
    const int slot = bid >> 3;
    const int work = xcd * BPX + slot;
    const int b    = work / CPB;
    const int f0   = (work - b * CPB) * FPB;

    const int t    = threadIdx.x;
    const int lane = t & 63;
    const int wid  = t >> 6;

    const int len = ilens[b];

    // ---- masked cumsum of ds: 512 elems, 2 per thread -------------------
    const int2 dv = reinterpret_cast<const int2*>(ds + b * TMAX)[t];
    const int e0 = 2 * t, e1 = 2 * t + 1;
    const int a = (e0 < len) ? dv.x : 0;
    const int c = (e1 < len) ? dv.y : 0;

    int x = a + c;
#pragma unroll
    for (int off = 1; off < 64; off <<= 1) {
        int v = __shfl_up(x, off);
        if (lane >= off) x += v;
    }
    if (lane == 63) s_wsum[wid] = x;
    __syncthreads();
    int prev = 0;
#pragma unroll
    for (int w = 0; w < NTH / 64; ++w)
        if (w < wid) prev += s_wsum[w];
    const int inc = x + prev;
    s_cum[e1] = inc;
    s_cum[e0] = inc - c;
    __syncthreads();

    int total = s_cum[TMAX - 1];
    if (total == 0) {               // block-uniform fallback: d = mask
        __syncthreads();
        s_cum[e0] = min(e0 + 1, len);
        s_cum[e1] = min(e1 + 1, len);
        total = len;
        __syncthreads();
    }

    const int base_out = (b * TOUT + f0) * D4;

    // ---- pad-only blocks: pure zero stream, fill-kernel shape -----------
    if (f0 >= total) {              // block-uniform
#pragma unroll
        for (int i = 0; i < ITER; ++i)
            __builtin_nontemporal_store((v4f)(0.f), &out[base_out + i * NTH + t]);
        return;
    }

    // ---- searchsorted(cum, f, side='right') for this block's frames -----
    if (t < FPB) {
        const int f = f0 + t;
        int lo = 0, hi = TMAX;
        while (lo < hi) {
            int mid = (lo + hi) >> 1;
            if (s_cum[mid] > f) hi = mid; else lo = mid + 1;
        }
        s_idx[t] = (lo < TMAX) ? lo : (TMAX - 1);   // clamped: always in-bounds
    }
    __syncthreads();

    // ---- gather: 24 float4/thread in 2 batches of 12 --------------------
    const int base_xs = b * TMAX * D4;
#pragma unroll
    for (int ib = 0; ib < ITER / BATCH; ++ib) {
        v4f v[BATCH];
        // phase 1: 12 unconditional loads, all in flight
#pragma unroll
        for (int j = 0; j < BATCH; ++j) {
            const int l   = (ib * BATCH + j) * NTH + t;
            const int fl  = l / D4;
            const int col = l - fl * D4;
            v[j] = xs[base_xs + s_idx[fl] * D4 + col];
        }
        // phase 2: pad-select (cndmask, no branch) + 12 stores
#pragma unroll
        for (int j = 0; j < BATCH; ++j) {
            const int l  = (ib * BATCH + j) * NTH + t;
            const int fl = l / D4;
            if (f0 + fl >= total) v[j] = (v4f)(0.f);
            __builtin_nontemporal_store(v[j], &out[base_out + l]);
        }
    }
}

extern "C" void kernel_launch(void* const* d_in, const int* in_sizes, int n_in,
                              void* d_out, int out_size, void* d_ws, size_t ws_size,
                              hipStream_t stream) {
    const float* xs    = (const float*)d_in[0];
    const int*   ds    = (const int*)d_in[1];
    const int*   ilens = (const int*)d_in[2];
    float*       out   = (float*)d_out;

    lr_fused_kernel<<<NBLK, NTH, 0, stream>>>(
        (const v4f*)xs, ds, ilens, (v4f*)out);
}